// Round 6
// baseline (537.883 us; speedup 1.0000x reference)
//
#include <hip/hip_runtime.h>
#include <hip/hip_bf16.h>

// dims (fixed per reference)
#define L_   2048
#define H_   2048
#define I_   2048
#define NH_  16
#define HPH_ 128
#define NS_  64
#define R_   128
#define NCH_ 32     // chunks
#define CT_  64     // steps per chunk

typedef __attribute__((ext_vector_type(8))) short s16x8;
typedef __attribute__((ext_vector_type(4))) float f32x4;

__device__ __forceinline__ short f2bf(float x) {
  unsigned u = __builtin_bit_cast(unsigned, x);
  u += 0x7fff + ((u >> 16) & 1);   // round-to-nearest-even
  return (short)(u >> 16);
}

// ---- pack weight W[K][N] (f32 row-major) -> Wp[(k>>3)][n][k&7] bf16 ----
__global__ __launch_bounds__(256) void pack_w(const float* __restrict__ W,
                                              short* __restrict__ Wp,
                                              int KN, int logN) {
  int idx = blockIdx.x * 256 + threadIdx.x;
  if (idx >= KN) return;
  int k = idx >> logN;
  int n = idx & ((1 << logN) - 1);
  Wp[((size_t)(k >> 3) << (logN + 3)) + ((size_t)n << 3) + (k & 7)] = f2bf(W[idx]);
}

__global__ __launch_bounds__(256) void cast_bf(const float* __restrict__ X,
                                               short* __restrict__ Xb, int nElem) {
  int idx = blockIdx.x * 256 + threadIdx.x;
  if (idx < nElem) Xb[idx] = f2bf(X[idx]);
}

// ---- bf16 MFMA GEMM: C[M,N] = A[M,K] * B[K,N], A row-major bf16, B packed ----
__global__ __launch_bounds__(256) void gemm_bf16(const short* __restrict__ A,
                                                 const short* __restrict__ Bp,
                                                 float* __restrict__ C,
                                                 int M, int N, int K) {
  int tid = threadIdx.x;
  int lane = tid & 63, wid = tid >> 6;
  int wr = wid >> 1, wc = wid & 1;
  int l15 = lane & 15, l16 = lane >> 4;
  int bm = blockIdx.x * 128, bn = blockIdx.y * 128;

  f32x4 acc[4][4] = {};

  const short* Ab = A + (size_t)(bm + wr * 64 + l15) * K + l16 * 8;
  const short* Bb = Bp + (size_t)l16 * N * 8 + (size_t)(bn + wc * 64 + l15) * 8;

#pragma unroll 2
  for (int k0 = 0; k0 < K; k0 += 32) {
    s16x8 a[4], b[4];
#pragma unroll
    for (int mi = 0; mi < 4; ++mi)
      a[mi] = *(const s16x8*)(Ab + (size_t)mi * 16 * K + k0);
#pragma unroll
    for (int ni = 0; ni < 4; ++ni)
      b[ni] = *(const s16x8*)(Bb + (size_t)k0 * N + ni * 128);
#pragma unroll
    for (int mi = 0; mi < 4; ++mi)
#pragma unroll
      for (int ni = 0; ni < 4; ++ni)
        acc[mi][ni] = __builtin_amdgcn_mfma_f32_16x16x32_bf16(a[mi], b[ni], acc[mi][ni], 0, 0, 0);
  }
#pragma unroll
  for (int mi = 0; mi < 4; ++mi) {
    int row0 = bm + wr * 64 + mi * 16 + l16 * 4;
#pragma unroll
    for (int ni = 0; ni < 4; ++ni) {
      int col = bn + wc * 64 + ni * 16 + l15;
#pragma unroll
      for (int r = 0; r < 4; ++r)
        C[(size_t)(row0 + r) * N + col] = acc[mi][ni][r];
    }
  }
}

// ---- causal depthwise conv (K=4) + SiLU; reads hs half of proj ----
__global__ __launch_bounds__(256) void conv_silu(const float* __restrict__ proj,
                                                 const float* __restrict__ convw,
                                                 float* __restrict__ hs,
                                                 short* __restrict__ hsb) {
  int idx = blockIdx.x * 256 + threadIdx.x;   // over L_*I_
  int t = idx >> 11, i = idx & (I_ - 1);
  int col = ((i >> 7) << 8) + 128 + (i & 127);  // head*256 + 128 + (i%128)
  float4 cw = *(const float4*)(convw + i * 4);
  const float* p = proj + (size_t)t * (2 * I_) + col;
  float acc = cw.w * p[0];
  if (t >= 1) acc += cw.z * p[-(2 * I_)];
  if (t >= 2) acc += cw.y * p[-(2 * I_) * 2];
  if (t >= 3) acc += cw.x * p[-(2 * I_) * 3];
  float h = acc / (1.f + __expf(-acc));   // silu
  hs[idx] = h;
  hsb[idx] = f2bf(h);
}

// ---- RMSNorms (B, C, ts) + dt = ts@dt_proj + softplus(dt + bias) ----
__global__ __launch_bounds__(256) void norm_dt(const float* __restrict__ sp,
                                               const float* __restrict__ Bw,
                                               const float* __restrict__ Cw,
                                               const float* __restrict__ dtw,
                                               const float* __restrict__ Wdt,
                                               const float* __restrict__ bias,
                                               float* __restrict__ Bo,
                                               float* __restrict__ Co,
                                               float* __restrict__ delta) {
  int lane = threadIdx.x & 63, w = threadIdx.x >> 6;
  int t = blockIdx.x * 4 + w;
  const float* row = sp + (size_t)t * 256;
  float v0 = row[lane], v1 = row[64 + lane], v2 = row[128 + lane], v3 = row[192 + lane];
  float sB = v0 * v0, sC = v1 * v1, sT = v2 * v2 + v3 * v3;
#pragma unroll
  for (int off = 32; off; off >>= 1) {
    sB += __shfl_xor(sB, off);
    sC += __shfl_xor(sC, off);
    sT += __shfl_xor(sT, off);
  }
  float rB = rsqrtf(sB * (1.f / 64) + 1e-6f);
  float rC = rsqrtf(sC * (1.f / 64) + 1e-6f);
  float rT = rsqrtf(sT * (1.f / 128) + 1e-6f);
  Bo[t * 64 + lane] = v0 * rB * Bw[lane];
  Co[t * 64 + lane] = v1 * rC * Cw[lane];
  float t2 = v2 * rT * dtw[lane], t3 = v3 * rT * dtw[64 + lane];
  float p[NH_];
  const float* w0 = Wdt + lane * NH_;
  const float* w1 = Wdt + (64 + lane) * NH_;
#pragma unroll
  for (int h = 0; h < NH_; ++h) p[h] = t2 * w0[h] + t3 * w1[h];
#pragma unroll
  for (int off = 32; off; off >>= 1)
#pragma unroll
    for (int h = 0; h < NH_; ++h) p[h] += __shfl_xor(p[h], off);
  if (lane == 0) {
#pragma unroll
    for (int h = 0; h < NH_; ++h) {
      float x = p[h] + bias[h];
      delta[t * NH_ + h] = (x > 20.f) ? x : log1pf(__expf(x));
    }
  }
}

// ---- per-(chunk, head) delta sums: sumd[c*16+h] = sum_{t in chunk} delta ----
__global__ __launch_bounds__(512) void chunk_sums(const float* __restrict__ delta,
                                                  float* __restrict__ sumd) {
  int t = threadIdx.x;          // 512 = 32 chunks * 16 heads
  int c = t >> 4, h = t & 15;
  float s = 0.f;
  const float* p = delta + (size_t)c * CT_ * NH_ + h;
#pragma unroll 8
  for (int j = 0; j < CT_; ++j) s += p[(size_t)j * NH_];
  sumd[t] = s;
}

// ======================= chunked selective scan =======================
// wave = channel i, lane = state n.  3 phases (exact by linearity of the
// recurrence): (1) local chunk scans from zero, (2) sequential combine over
// 32 chunks, (3) per-chunk recompute with known incoming state + y-reduce.

__device__ __forceinline__ float rdlane(float v, int l) {
  return __builtin_bit_cast(float, __builtin_amdgcn_readlane(__builtin_bit_cast(int, v), l));
}

// XOR-swizzled [n][t] index (float4 granule along t, permuted by n&15)
__device__ __forceinline__ int bidx(int n, int t) {
  return n * 64 + ((((t >> 2) ^ (n & 15)) << 2) | (t & 3));
}

// ---- phase 1: local scan (state only, no y) ----
__global__ __launch_bounds__(512) void scan1(const float* __restrict__ hs,     // [L, I]
                                             const float* __restrict__ Bm,     // [L, N]
                                             const float* __restrict__ delta,  // [L, NH]
                                             const float* __restrict__ A,      // [I, N]
                                             float* __restrict__ st) {         // [NCH][I][N]
  __shared__ float sB[64 * 64];
  __shared__ float su_t[8][68], sd_t[64];
  int tid = threadIdx.x;
  int lane = tid & 63, w = tid >> 6;
  int c0 = blockIdx.x * 8;
  int chunk = blockIdx.y;
  int t0 = chunk * CT_;
  int i = c0 + w;
  int head = c0 >> 7;
  float aPre = A[i * 64 + lane] * 1.4426950408889634f;
  int ww = tid & 7, tt = tid >> 3;
  int l15 = lane & 15;
  int ldsbase = lane << 6;

  // stage B (float4 global loads, swizzled transposed LDS writes)
  const float4* B4 = (const float4*)(Bm + t0 * 64);
#pragma unroll
  for (int r = 0; r < 2; ++r) {
    int f4 = r * 512 + tid;
    float4 bv = B4[f4];
    int t = f4 >> 4, n0 = (f4 & 15) << 2;
#pragma unroll
    for (int j = 0; j < 4; ++j) sB[bidx(n0 + j, t)] = (&bv.x)[j];
  }
  su_t[ww][tt] = hs[(size_t)(t0 + tt) * I_ + c0 + ww];
  if (tid < CT_) sd_t[tid] = delta[(t0 + tid) * NH_ + head];
  __syncthreads();

  float u_r = su_t[w][lane];
  float d_r = sd_t[lane];
  float s = 0.f;

#pragma unroll 1
  for (int g = 0; g < 8; ++g) {
    int tg = g * 8;
    float dsj[8], usj[8];
#pragma unroll
    for (int j = 0; j < 8; ++j) {
      dsj[j] = rdlane(d_r, tg + j);
      usj[j] = rdlane(u_r, tg + j);
    }
    int g2 = tg >> 2;
    int off_lo = ldsbase + ((g2 ^ l15) << 2);
    int off_hi = ldsbase + (((g2 + 1) ^ l15) << 2);
    float4 b_lo = *(const float4*)&sB[off_lo];
    float4 b_hi = *(const float4*)&sB[off_hi];
#pragma unroll
    for (int j = 0; j < 8; ++j) {
      float bb = (j < 4) ? (&b_lo.x)[j] : (&b_hi.x)[j - 4];
      float dA = exp2f(dsj[j] * aPre);
      s = s * dA + (dsj[j] * usj[j]) * bb;
    }
  }
  st[(size_t)chunk * (I_ * 64) + (size_t)i * 64 + lane] = s;
}

// ---- phase 2: sequential combine; rewrites st[c] with INCOMING state ----
__global__ __launch_bounds__(512) void scan2(const float* __restrict__ A,
                                             const float* __restrict__ sumd,  // [NCH*16]
                                             float* __restrict__ st) {        // [NCH][I][N]
  int g = blockIdx.x * 512 + threadIdx.x;   // over I_*64
  int h = g >> 13;                           // (g>>6)>>7
  float aPre = A[g] * 1.4426950408889634f;
  float s = 0.f;
#pragma unroll 1
  for (int c = 0; c < NCH_; ++c) {
    float gfac = exp2f(aPre * sumd[c * 16 + h]);
    float loc = st[(size_t)c * (I_ * 64) + g];
    st[(size_t)c * (I_ * 64) + g] = s;       // incoming state for chunk c
    s = s * gfac + loc;
  }
}

// ---- phase 3: per-chunk recompute + y reduce + fused epilogue ----
__global__ __launch_bounds__(512) void scan3(const float* __restrict__ hs,     // [L, I]
                                             const float* __restrict__ Bm,     // [L, N]
                                             const float* __restrict__ Cm,     // [L, N]
                                             const float* __restrict__ delta,  // [L, NH]
                                             const float* __restrict__ A,      // [I, N]
                                             const float* __restrict__ Dv,     // [I]
                                             const float* __restrict__ proj,   // [L, 2I]
                                             const float* __restrict__ st,     // [NCH][I][N]
                                             short* __restrict__ ybf) {        // [L, I] bf16
  __shared__ float sBC[2][64 * 64];
  __shared__ float su_t[8][68], sd_t[64];
  __shared__ float yb[CT_][9];
  int tid = threadIdx.x;
  int lane = tid & 63, w = tid >> 6;
  int c0 = blockIdx.x * 8;
  int chunk = blockIdx.y;
  int t0 = chunk * CT_;
  int i = c0 + w;
  int head = c0 >> 7;
  float aPre = A[i * 64 + lane] * 1.4426950408889634f;
  float s = st[(size_t)chunk * (I_ * 64) + (size_t)i * 64 + lane];
  int ww = tid & 7, tt = tid >> 3;
  int l15 = lane & 15;
  int ldsbase = lane << 6;

  // stage B/C
  const float4* B4 = (const float4*)(Bm + t0 * 64);
  const float4* C4 = (const float4*)(Cm + t0 * 64);
#pragma unroll
  for (int r = 0; r < 2; ++r) {
    int f4 = r * 512 + tid;
    float4 bv = B4[f4];
    float4 cv = C4[f4];
    int t = f4 >> 4, n0 = (f4 & 15) << 2;
#pragma unroll
    for (int j = 0; j < 4; ++j) {
      sBC[0][bidx(n0 + j, t)] = (&bv.x)[j];
      sBC[1][bidx(n0 + j, t)] = (&cv.x)[j];
    }
  }
  su_t[ww][tt] = hs[(size_t)(t0 + tt) * I_ + c0 + ww];
  if (tid < CT_) sd_t[tid] = delta[(t0 + tid) * NH_ + head];
  __syncthreads();

  float u_r = su_t[w][lane];
  float d_r = sd_t[lane];

#pragma unroll 1
  for (int g = 0; g < 8; ++g) {
    int tg = g * 8;
    float dsj[8], usj[8];
#pragma unroll
    for (int j = 0; j < 8; ++j) {
      dsj[j] = rdlane(d_r, tg + j);
      usj[j] = rdlane(u_r, tg + j);
    }
    int g2 = tg >> 2;
    int off_lo = ldsbase + ((g2 ^ l15) << 2);
    int off_hi = ldsbase + (((g2 + 1) ^ l15) << 2);
    float4 b_lo = *(const float4*)&sBC[0][off_lo];
    float4 b_hi = *(const float4*)&sBC[0][off_hi];
    float4 c_lo = *(const float4*)&sBC[1][off_lo];
    float4 c_hi = *(const float4*)&sBC[1][off_hi];

    float dA[8], xx[8];
#pragma unroll
    for (int j = 0; j < 8; ++j) {
      float bb = (j < 4) ? (&b_lo.x)[j] : (&b_hi.x)[j - 4];
      dA[j] = exp2f(dsj[j] * aPre);
      xx[j] = (dsj[j] * usj[j]) * bb;
    }
    float pp[8];
#pragma unroll
    for (int j = 0; j < 8; ++j) {
      s = s * dA[j] + xx[j];
      float cc = (j < 4) ? (&c_lo.x)[j] : (&c_hi.x)[j - 4];
      pp[j] = s * cc;
    }
    // interleaved fold-select tree (17 shfl) — round-5-verified
    bool b3 = lane & 8, b4 = lane & 16, b5 = lane & 32;
#pragma unroll
    for (int j = 0; j < 8; ++j) pp[j] += __shfl_xor(pp[j], 8);
    float q0 = b3 ? pp[1] : pp[0];
    float q1 = b3 ? pp[3] : pp[2];
    float q2 = b3 ? pp[5] : pp[4];
    float q3 = b3 ? pp[7] : pp[6];
    q0 += __shfl_xor(q0, 16);
    q1 += __shfl_xor(q1, 16);
    q2 += __shfl_xor(q2, 16);
    q3 += __shfl_xor(q3, 16);
    float r0 = b4 ? q1 : q0;
    float r1 = b4 ? q3 : q2;
    r0 += __shfl_xor(r0, 32);
    r1 += __shfl_xor(r1, 32);
    float wv = b5 ? r1 : r0;
    wv += __shfl_xor(wv, 1);
    wv += __shfl_xor(wv, 2);
    wv += __shfl_xor(wv, 4);
    if ((lane & 7) == 0) yb[tg + (lane >> 3)][w] = wv;
  }
  __syncthreads();

  // epilogue: y = (ys + D*hs) * silu(gate) -> bf16
  {
    int t = t0 + tt, ii = c0 + ww;
    float g = proj[(size_t)t * (2 * I_) + ((ii >> 7) << 8) + (ii & 127)];
    float sg = g / (1.f + __expf(-g));
    float yv = (yb[tt][ww] + Dv[ii] * su_t[ww][tt]) * sg;
    ybf[(size_t)t * I_ + ii] = f2bf(yv);
  }
}

extern "C" void kernel_launch(void* const* d_in, const int* in_sizes, int n_in,
                              void* d_out, int out_size, void* d_ws, size_t ws_size,
                              hipStream_t stream) {
  const float* hidden  = (const float*)d_in[0];
  const float* inproj  = (const float*)d_in[1];
  const float* convw   = (const float*)d_in[2];
  const float* bcdtw   = (const float*)d_in[3];
  const float* dtnw    = (const float*)d_in[4];
  const float* Bnw     = (const float*)d_in[5];
  const float* Cnw     = (const float*)d_in[6];
  const float* dtpw    = (const float*)d_in[7];
  const float* dtbias  = (const float*)d_in[8];
  const float* Amat    = (const float*)d_in[9];
  const float* Dvec    = (const float*)d_in[10];
  const float* outproj = (const float*)d_in[11];
  float* out = (float*)d_out;

  char* ws = (char*)d_ws;
  short* inproj_p  = (short*)ws; ws += (size_t)H_ * 2 * I_ * 2;   // 16 MB
  short* bcdt_p    = (short*)ws; ws += (size_t)I_ * 256 * 2;
  short* outproj_p = (short*)ws; ws += (size_t)I_ * H_ * 2;
  short* hid_b     = (short*)ws; ws += (size_t)L_ * H_ * 2;
  float* proj      = (float*)ws; ws += (size_t)L_ * 2 * I_ * 4;
  float* hs        = (float*)ws; ws += (size_t)L_ * I_ * 4;
  short* hs_b      = (short*)ws; ws += (size_t)L_ * I_ * 2;
  float* ssmp      = (float*)ws; ws += (size_t)L_ * 256 * 4;
  float* Bmat      = (float*)ws; ws += (size_t)L_ * NS_ * 4;
  float* Cmat      = (float*)ws; ws += (size_t)L_ * NS_ * 4;
  float* delta     = (float*)ws; ws += (size_t)L_ * NH_ * 4;
  short* y_b       = (short*)ws; ws += (size_t)L_ * I_ * 2;
  float* sumd      = (float*)ws; ws += NCH_ * 16 * 4;
  // chunk-state buffer [NCH][I][64] f32 = 16 MB: aliases inproj_p, which is
  // dead after gemm1 (stream-ordered; re-packed at the start of every launch).
  float* sstate    = (float*)inproj_p;

  pack_w<<<(H_ * 2 * I_ + 255) / 256, 256, 0, stream>>>(inproj, inproj_p, H_ * 2 * I_, 12);
  pack_w<<<(I_ * 256 + 255) / 256, 256, 0, stream>>>(bcdtw, bcdt_p, I_ * 256, 8);
  pack_w<<<(I_ * H_ + 255) / 256, 256, 0, stream>>>(outproj, outproj_p, I_ * H_, 11);
  cast_bf<<<(L_ * H_ + 255) / 256, 256, 0, stream>>>(hidden, hid_b, L_ * H_);

  gemm_bf16<<<dim3(L_ / 128, (2 * I_) / 128), 256, 0, stream>>>(hid_b, inproj_p, proj, L_, 2 * I_, H_);
  conv_silu<<<(L_ * I_) / 256, 256, 0, stream>>>(proj, convw, hs, hs_b);
  gemm_bf16<<<dim3(L_ / 128, 256 / 128), 256, 0, stream>>>(hs_b, bcdt_p, ssmp, L_, 256, I_);
  norm_dt<<<L_ / 4, 256, 0, stream>>>(ssmp, Bnw, Cnw, dtnw, dtpw, dtbias, Bmat, Cmat, delta);

  chunk_sums<<<1, 512, 0, stream>>>(delta, sumd);
  scan1<<<dim3(I_ / 8, NCH_), 512, 0, stream>>>(hs, Bmat, delta, Amat, sstate);
  scan2<<<(I_ * 64) / 512, 512, 0, stream>>>(Amat, sumd, sstate);
  scan3<<<dim3(I_ / 8, NCH_), 512, 0, stream>>>(hs, Bmat, Cmat, delta, Amat, Dvec, proj, sstate, y_b);

  gemm_bf16<<<dim3(L_ / 128, H_ / 128), 256, 0, stream>>>(y_b, outproj_p, out, L_, H_, I_);
}

// Round 7
// 378.074 us; speedup vs baseline: 1.4227x; 1.4227x over previous
//
#include <hip/hip_runtime.h>
#include <hip/hip_bf16.h>

// dims (fixed per reference)
#define L_   2048
#define H_   2048
#define I_   2048
#define NH_  16
#define HPH_ 128
#define NS_  64
#define R_   128
#define NCH_ 32     // chunks
#define CT_  64     // steps per chunk

typedef __attribute__((ext_vector_type(8))) short s16x8;
typedef __attribute__((ext_vector_type(4))) float f32x4;

__device__ __forceinline__ short f2bf(float x) {
  unsigned u = __builtin_bit_cast(unsigned, x);
  u += 0x7fff + ((u >> 16) & 1);   // round-to-nearest-even
  return (short)(u >> 16);
}

// ---- pack weight W[K][N] (f32 row-major) -> Wp[(k>>3)][n][k&7] bf16 ----
__global__ __launch_bounds__(256) void pack_w(const float* __restrict__ W,
                                              short* __restrict__ Wp,
                                              int KN, int logN) {
  int idx = blockIdx.x * 256 + threadIdx.x;
  if (idx >= KN) return;
  int k = idx >> logN;
  int n = idx & ((1 << logN) - 1);
  Wp[((size_t)(k >> 3) << (logN + 3)) + ((size_t)n << 3) + (k & 7)] = f2bf(W[idx]);
}

__global__ __launch_bounds__(256) void cast_bf(const float* __restrict__ X,
                                               short* __restrict__ Xb, int nElem) {
  int idx = blockIdx.x * 256 + threadIdx.x;
  if (idx < nElem) Xb[idx] = f2bf(X[idx]);
}

// ---- bf16 MFMA GEMM: C[M,N] = A[M,K] * B[K,N], A row-major bf16, B packed ----
__global__ __launch_bounds__(256) void gemm_bf16(const short* __restrict__ A,
                                                 const short* __restrict__ Bp,
                                                 float* __restrict__ C,
                                                 int M, int N, int K) {
  int tid = threadIdx.x;
  int lane = tid & 63, wid = tid >> 6;
  int wr = wid >> 1, wc = wid & 1;
  int l15 = lane & 15, l16 = lane >> 4;
  int bm = blockIdx.x * 128, bn = blockIdx.y * 128;

  f32x4 acc[4][4] = {};

  const short* Ab = A + (size_t)(bm + wr * 64 + l15) * K + l16 * 8;
  const short* Bb = Bp + (size_t)l16 * N * 8 + (size_t)(bn + wc * 64 + l15) * 8;

#pragma unroll 2
  for (int k0 = 0; k0 < K; k0 += 32) {
    s16x8 a[4], b[4];
#pragma unroll
    for (int mi = 0; mi < 4; ++mi)
      a[mi] = *(const s16x8*)(Ab + (size_t)mi * 16 * K + k0);
#pragma unroll
    for (int ni = 0; ni < 4; ++ni)
      b[ni] = *(const s16x8*)(Bb + (size_t)k0 * N + ni * 128);
#pragma unroll
    for (int mi = 0; mi < 4; ++mi)
#pragma unroll
      for (int ni = 0; ni < 4; ++ni)
        acc[mi][ni] = __builtin_amdgcn_mfma_f32_16x16x32_bf16(a[mi], b[ni], acc[mi][ni], 0, 0, 0);
  }
#pragma unroll
  for (int mi = 0; mi < 4; ++mi) {
    int row0 = bm + wr * 64 + mi * 16 + l16 * 4;
#pragma unroll
    for (int ni = 0; ni < 4; ++ni) {
      int col = bn + wc * 64 + ni * 16 + l15;
#pragma unroll
      for (int r = 0; r < 4; ++r)
        C[(size_t)(row0 + r) * N + col] = acc[mi][ni][r];
    }
  }
}

// ---- causal depthwise conv (K=4) + SiLU; reads hs half of proj ----
__global__ __launch_bounds__(256) void conv_silu(const float* __restrict__ proj,
                                                 const float* __restrict__ convw,
                                                 float* __restrict__ hs,
                                                 short* __restrict__ hsb) {
  int idx = blockIdx.x * 256 + threadIdx.x;   // over L_*I_
  int t = idx >> 11, i = idx & (I_ - 1);
  int col = ((i >> 7) << 8) + 128 + (i & 127);  // head*256 + 128 + (i%128)
  float4 cw = *(const float4*)(convw + i * 4);
  const float* p = proj + (size_t)t * (2 * I_) + col;
  float acc = cw.w * p[0];
  if (t >= 1) acc += cw.z * p[-(2 * I_)];
  if (t >= 2) acc += cw.y * p[-(2 * I_) * 2];
  if (t >= 3) acc += cw.x * p[-(2 * I_) * 3];
  float h = acc / (1.f + __expf(-acc));   // silu
  hs[idx] = h;
  hsb[idx] = f2bf(h);
}

// ---- RMSNorms (B, C, ts) + dt = ts@dt_proj + softplus(dt + bias) ----
__global__ __launch_bounds__(256) void norm_dt(const float* __restrict__ sp,
                                               const float* __restrict__ Bw,
                                               const float* __restrict__ Cw,
                                               const float* __restrict__ dtw,
                                               const float* __restrict__ Wdt,
                                               const float* __restrict__ bias,
                                               float* __restrict__ Bo,
                                               float* __restrict__ Co,
                                               float* __restrict__ delta) {
  int lane = threadIdx.x & 63, w = threadIdx.x >> 6;
  int t = blockIdx.x * 4 + w;
  const float* row = sp + (size_t)t * 256;
  float v0 = row[lane], v1 = row[64 + lane], v2 = row[128 + lane], v3 = row[192 + lane];
  float sB = v0 * v0, sC = v1 * v1, sT = v2 * v2 + v3 * v3;
#pragma unroll
  for (int off = 32; off; off >>= 1) {
    sB += __shfl_xor(sB, off);
    sC += __shfl_xor(sC, off);
    sT += __shfl_xor(sT, off);
  }
  float rB = rsqrtf(sB * (1.f / 64) + 1e-6f);
  float rC = rsqrtf(sC * (1.f / 64) + 1e-6f);
  float rT = rsqrtf(sT * (1.f / 128) + 1e-6f);
  Bo[t * 64 + lane] = v0 * rB * Bw[lane];
  Co[t * 64 + lane] = v1 * rC * Cw[lane];
  float t2 = v2 * rT * dtw[lane], t3 = v3 * rT * dtw[64 + lane];
  float p[NH_];
  const float* w0 = Wdt + lane * NH_;
  const float* w1 = Wdt + (64 + lane) * NH_;
#pragma unroll
  for (int h = 0; h < NH_; ++h) p[h] = t2 * w0[h] + t3 * w1[h];
#pragma unroll
  for (int off = 32; off; off >>= 1)
#pragma unroll
    for (int h = 0; h < NH_; ++h) p[h] += __shfl_xor(p[h], off);
  if (lane == 0) {
#pragma unroll
    for (int h = 0; h < NH_; ++h) {
      float x = p[h] + bias[h];
      delta[t * NH_ + h] = (x > 20.f) ? x : log1pf(__expf(x));
    }
  }
}

// ---- per-(chunk, head) delta sums: sumd[c*16+h] = sum_{t in chunk} delta ----
__global__ __launch_bounds__(512) void chunk_sums(const float* __restrict__ delta,
                                                  float* __restrict__ sumd) {
  int t = threadIdx.x;          // 512 = 32 chunks * 16 heads
  int c = t >> 4, h = t & 15;
  float s = 0.f;
  const float* p = delta + (size_t)c * CT_ * NH_ + h;
#pragma unroll 8
  for (int j = 0; j < CT_; ++j) s += p[(size_t)j * NH_];
  sumd[t] = s;
}

// ======================= chunked selective scan (lane = channel) =========
// Each thread owns one channel i; s[0..63] and A[i][0..63] live in VGPRs.
// B/C[t][n] are wave-uniform LDS broadcasts; delta via readlane; u/gate are
// coalesced per-lane global loads (1-deep pipelined).  No cross-lane reduce.
// 3 exact phases: local chunk scan -> sequential combine -> recompute+y.
// st layout: [chunk][n][i]  (coalesced in i for every access).

__device__ __forceinline__ float rdlane(float v, int l) {
  return __builtin_bit_cast(float, __builtin_amdgcn_readlane(__builtin_bit_cast(int, v), l));
}

// ---- phase 1: local scan from zero (state only) ----
__global__ __launch_bounds__(256, 1) void scan1(const float* __restrict__ hs,     // [L, I] (+1 pad row)
                                                const float* __restrict__ Bm,     // [L, N]
                                                const float* __restrict__ delta,  // [L, NH]
                                                const float* __restrict__ A,      // [I, N]
                                                float* __restrict__ st) {         // [NCH][N][I]
  __shared__ float sB[CT_ * 64];             // [t][n], plain layout
  int tid = threadIdx.x;
  int lane = tid & 63;
  int i = blockIdx.x * 256 + tid;
  int chunk = blockIdx.y;
  int t0 = chunk * CT_;
  int head = i >> 7;                          // wave-uniform

  // stage B chunk (contiguous 16KB copy)
  {
    const float4* B4 = (const float4*)(Bm + (size_t)t0 * 64);
    float4* S4 = (float4*)sB;
#pragma unroll
    for (int r = 0; r < 4; ++r) S4[r * 256 + tid] = B4[r * 256 + tid];
  }
  // per-lane delta register: lane l holds delta[t0+l, head]
  float d_r = delta[(size_t)(t0 + lane) * NH_ + head];

  float aR[64], s[64];
#pragma unroll
  for (int q = 0; q < 16; ++q) {
    float4 av = *(const float4*)&A[(size_t)i * 64 + q * 4];
    aR[q * 4 + 0] = av.x; aR[q * 4 + 1] = av.y;
    aR[q * 4 + 2] = av.z; aR[q * 4 + 3] = av.w;
  }
#pragma unroll
  for (int n = 0; n < 64; ++n) s[n] = 0.f;
  __syncthreads();

  const float* up = hs + (size_t)t0 * I_ + i;
  float u_next = up[0];
#pragma unroll 1
  for (int t = 0; t < CT_; ++t) {
    float u = u_next;
    u_next = up[(size_t)(t + 1) * I_];        // over-reads 1 padded row at end
    float dlt = rdlane(d_r, t);
    float du = dlt * u;
    const float* bt = &sB[t * 64];
#pragma unroll
    for (int ng = 0; ng < 16; ++ng) {
      float4 b4 = *(const float4*)&bt[ng * 4];
#pragma unroll
      for (int j = 0; j < 4; ++j) {
        int n = ng * 4 + j;
        float dA = __expf(dlt * aR[n]);
        s[n] = s[n] * dA + du * (&b4.x)[j];
      }
    }
  }
#pragma unroll
  for (int n = 0; n < 64; ++n)
    st[((size_t)chunk << 17) + (n << 11) + i] = s[n];
}

// ---- phase 2: sequential combine; rewrites st[c] with INCOMING state ----
__global__ __launch_bounds__(512) void scan2(const float* __restrict__ A,
                                             const float* __restrict__ sumd,  // [NCH*16]
                                             float* __restrict__ st) {        // [NCH][N][I]
  int g = blockIdx.x * 512 + threadIdx.x;    // over N*I = 131072
  int i = g & (I_ - 1), n = g >> 11;
  int h = i >> 7;
  float aV = A[((size_t)i << 6) + n];
  float s = 0.f;
#pragma unroll 1
  for (int c = 0; c < NCH_; ++c) {
    float gfac = __expf(aV * sumd[c * 16 + h]);
    float loc = st[((size_t)c << 17) + g];
    st[((size_t)c << 17) + g] = s;            // incoming state for chunk c
    s = s * gfac + loc;
  }
}

// ---- phase 3: recompute with incoming state + in-register y + epilogue ----
__global__ __launch_bounds__(256, 1) void scan3(const float* __restrict__ hs,     // [L, I] (+pad)
                                                const float* __restrict__ Bm,     // [L, N]
                                                const float* __restrict__ Cm,     // [L, N]
                                                const float* __restrict__ delta,  // [L, NH]
                                                const float* __restrict__ A,      // [I, N]
                                                const float* __restrict__ Dv,     // [I]
                                                const float* __restrict__ proj,   // [L, 2I]
                                                const float* __restrict__ st,     // [NCH][N][I]
                                                short* __restrict__ ybf) {        // [L, I] bf16
  __shared__ float sB[CT_ * 64], sC[CT_ * 64];
  int tid = threadIdx.x;
  int lane = tid & 63;
  int i = blockIdx.x * 256 + tid;
  int chunk = blockIdx.y;
  int t0 = chunk * CT_;
  int head = i >> 7;

  {
    const float4* B4 = (const float4*)(Bm + (size_t)t0 * 64);
    const float4* C4 = (const float4*)(Cm + (size_t)t0 * 64);
    float4* SB4 = (float4*)sB;
    float4* SC4 = (float4*)sC;
#pragma unroll
    for (int r = 0; r < 4; ++r) {
      SB4[r * 256 + tid] = B4[r * 256 + tid];
      SC4[r * 256 + tid] = C4[r * 256 + tid];
    }
  }
  float d_r = delta[(size_t)(t0 + lane) * NH_ + head];

  float aR[64], s[64];
#pragma unroll
  for (int q = 0; q < 16; ++q) {
    float4 av = *(const float4*)&A[(size_t)i * 64 + q * 4];
    aR[q * 4 + 0] = av.x; aR[q * 4 + 1] = av.y;
    aR[q * 4 + 2] = av.z; aR[q * 4 + 3] = av.w;
  }
#pragma unroll
  for (int n = 0; n < 64; ++n)
    s[n] = st[((size_t)chunk << 17) + (n << 11) + i];
  float D_i = Dv[i];
  __syncthreads();

  const float* up = hs + (size_t)t0 * I_ + i;
  const float* gp = proj + (size_t)t0 * (2 * I_) + ((i >> 7) << 8) + (i & 127);
  short* yp = ybf + (size_t)t0 * I_ + i;
  float u_next = up[0];
  float g_next = gp[0];
#pragma unroll 1
  for (int t = 0; t < CT_; ++t) {
    float u = u_next, gv = g_next;
    u_next = up[(size_t)(t + 1) * I_];          // over-reads padded row at end
    g_next = gp[(size_t)(t + 1) * (2 * I_)];    // over-reads into next ws buffer
    float dlt = rdlane(d_r, t);
    float du = dlt * u;
    const float* bt = &sB[t * 64];
    const float* ct = &sC[t * 64];
    float y0 = 0.f, y1 = 0.f, y2 = 0.f, y3 = 0.f;
#pragma unroll
    for (int ng = 0; ng < 16; ++ng) {
      float4 b4 = *(const float4*)&bt[ng * 4];
      float4 c4 = *(const float4*)&ct[ng * 4];
#pragma unroll
      for (int j = 0; j < 4; ++j) {
        int n = ng * 4 + j;
        float dA = __expf(dlt * aR[n]);
        s[n] = s[n] * dA + du * (&b4.x)[j];
        float pv = s[n] * (&c4.x)[j];
        if (j == 0) y0 += pv; else if (j == 1) y1 += pv;
        else if (j == 2) y2 += pv; else y3 += pv;
      }
    }
    float y = (y0 + y1) + (y2 + y3) + D_i * u;
    float sg = gv / (1.f + __expf(-gv));
    yp[(size_t)t * I_] = f2bf(y * sg);
  }
}

extern "C" void kernel_launch(void* const* d_in, const int* in_sizes, int n_in,
                              void* d_out, int out_size, void* d_ws, size_t ws_size,
                              hipStream_t stream) {
  const float* hidden  = (const float*)d_in[0];
  const float* inproj  = (const float*)d_in[1];
  const float* convw   = (const float*)d_in[2];
  const float* bcdtw   = (const float*)d_in[3];
  const float* dtnw    = (const float*)d_in[4];
  const float* Bnw     = (const float*)d_in[5];
  const float* Cnw     = (const float*)d_in[6];
  const float* dtpw    = (const float*)d_in[7];
  const float* dtbias  = (const float*)d_in[8];
  const float* Amat    = (const float*)d_in[9];
  const float* Dvec    = (const float*)d_in[10];
  const float* outproj = (const float*)d_in[11];
  float* out = (float*)d_out;

  char* ws = (char*)d_ws;
  short* inproj_p  = (short*)ws; ws += (size_t)H_ * 2 * I_ * 2;   // 16 MB
  short* bcdt_p    = (short*)ws; ws += (size_t)I_ * 256 * 2;
  short* outproj_p = (short*)ws; ws += (size_t)I_ * H_ * 2;
  short* hid_b     = (short*)ws; ws += (size_t)L_ * H_ * 2;
  float* proj      = (float*)ws; ws += (size_t)L_ * 2 * I_ * 4;
  float* hs        = (float*)ws; ws += (size_t)(L_ + 1) * I_ * 4; // +1 pad row
  short* hs_b      = (short*)ws; ws += (size_t)L_ * I_ * 2;
  float* ssmp      = (float*)ws; ws += (size_t)L_ * 256 * 4;
  float* Bmat      = (float*)ws; ws += (size_t)L_ * NS_ * 4;
  float* Cmat      = (float*)ws; ws += (size_t)L_ * NS_ * 4;
  float* delta     = (float*)ws; ws += (size_t)L_ * NH_ * 4;
  short* y_b       = (short*)ws; ws += (size_t)L_ * I_ * 2;
  float* sumd      = (float*)ws; ws += NCH_ * 16 * 4;
  // chunk-state buffer [NCH][N][I] f32 = 16 MB: aliases inproj_p, dead after
  // gemm1 (stream-ordered; re-packed at the start of every launch).
  float* sstate    = (float*)inproj_p;

  pack_w<<<(H_ * 2 * I_ + 255) / 256, 256, 0, stream>>>(inproj, inproj_p, H_ * 2 * I_, 12);
  pack_w<<<(I_ * 256 + 255) / 256, 256, 0, stream>>>(bcdtw, bcdt_p, I_ * 256, 8);
  pack_w<<<(I_ * H_ + 255) / 256, 256, 0, stream>>>(outproj, outproj_p, I_ * H_, 11);
  cast_bf<<<(L_ * H_ + 255) / 256, 256, 0, stream>>>(hidden, hid_b, L_ * H_);

  gemm_bf16<<<dim3(L_ / 128, (2 * I_) / 128), 256, 0, stream>>>(hid_b, inproj_p, proj, L_, 2 * I_, H_);
  conv_silu<<<(L_ * I_) / 256, 256, 0, stream>>>(proj, convw, hs, hs_b);
  gemm_bf16<<<dim3(L_ / 128, 256 / 128), 256, 0, stream>>>(hs_b, bcdt_p, ssmp, L_, 256, I_);
  norm_dt<<<L_ / 4, 256, 0, stream>>>(ssmp, Bnw, Cnw, dtnw, dtpw, dtbias, Bmat, Cmat, delta);

  chunk_sums<<<1, 512, 0, stream>>>(delta, sumd);
  scan1<<<dim3(I_ / 256, NCH_), 256, 0, stream>>>(hs, Bmat, delta, Amat, sstate);
  scan2<<<(I_ * 64) / 512, 512, 0, stream>>>(Amat, sumd, sstate);
  scan3<<<dim3(I_ / 256, NCH_), 256, 0, stream>>>(hs, Bmat, Cmat, delta, Amat, Dvec, proj, sstate, y_b);

  gemm_bf16<<<dim3(L_ / 128, H_ / 128), 256, 0, stream>>>(y_b, outproj_p, out, L_, H_, I_);
}

// Round 8
// 372.290 us; speedup vs baseline: 1.4448x; 1.0155x over previous
//
#include <hip/hip_runtime.h>
#include <hip/hip_bf16.h>

// dims (fixed per reference)
#define L_   2048
#define H_   2048
#define I_   2048
#define NH_  16
#define HPH_ 128
#define NS_  64
#define R_   128
#define NCH_ 64     // chunks
#define CT_  32     // steps per chunk

typedef __attribute__((ext_vector_type(8))) short s16x8;
typedef __attribute__((ext_vector_type(4))) float f32x4;

__device__ __forceinline__ short f2bf(float x) {
  unsigned u = __builtin_bit_cast(unsigned, x);
  u += 0x7fff + ((u >> 16) & 1);   // round-to-nearest-even
  return (short)(u >> 16);
}

// ---- pack weight W[K][N] (f32 row-major) -> Wp[(k>>3)][n][k&7] bf16 ----
__global__ __launch_bounds__(256) void pack_w(const float* __restrict__ W,
                                              short* __restrict__ Wp,
                                              int KN, int logN) {
  int idx = blockIdx.x * 256 + threadIdx.x;
  if (idx >= KN) return;
  int k = idx >> logN;
  int n = idx & ((1 << logN) - 1);
  Wp[((size_t)(k >> 3) << (logN + 3)) + ((size_t)n << 3) + (k & 7)] = f2bf(W[idx]);
}

__global__ __launch_bounds__(256) void cast_bf(const float* __restrict__ X,
                                               short* __restrict__ Xb, int nElem) {
  int idx = blockIdx.x * 256 + threadIdx.x;
  if (idx < nElem) Xb[idx] = f2bf(X[idx]);
}

// ---- bf16 MFMA GEMM: C[M,N] = A[M,K] * B[K,N], A row-major bf16, B packed ----
__global__ __launch_bounds__(256) void gemm_bf16(const short* __restrict__ A,
                                                 const short* __restrict__ Bp,
                                                 float* __restrict__ C,
                                                 int M, int N, int K) {
  int tid = threadIdx.x;
  int lane = tid & 63, wid = tid >> 6;
  int wr = wid >> 1, wc = wid & 1;
  int l15 = lane & 15, l16 = lane >> 4;
  int bm = blockIdx.x * 128, bn = blockIdx.y * 128;

  f32x4 acc[4][4] = {};

  const short* Ab = A + (size_t)(bm + wr * 64 + l15) * K + l16 * 8;
  const short* Bb = Bp + (size_t)l16 * N * 8 + (size_t)(bn + wc * 64 + l15) * 8;

#pragma unroll 2
  for (int k0 = 0; k0 < K; k0 += 32) {
    s16x8 a[4], b[4];
#pragma unroll
    for (int mi = 0; mi < 4; ++mi)
      a[mi] = *(const s16x8*)(Ab + (size_t)mi * 16 * K + k0);
#pragma unroll
    for (int ni = 0; ni < 4; ++ni)
      b[ni] = *(const s16x8*)(Bb + (size_t)k0 * N + ni * 128);
#pragma unroll
    for (int mi = 0; mi < 4; ++mi)
#pragma unroll
      for (int ni = 0; ni < 4; ++ni)
        acc[mi][ni] = __builtin_amdgcn_mfma_f32_16x16x32_bf16(a[mi], b[ni], acc[mi][ni], 0, 0, 0);
  }
#pragma unroll
  for (int mi = 0; mi < 4; ++mi) {
    int row0 = bm + wr * 64 + mi * 16 + l16 * 4;
#pragma unroll
    for (int ni = 0; ni < 4; ++ni) {
      int col = bn + wc * 64 + ni * 16 + l15;
#pragma unroll
      for (int r = 0; r < 4; ++r)
        C[(size_t)(row0 + r) * N + col] = acc[mi][ni][r];
    }
  }
}

// ---- causal depthwise conv (K=4) + SiLU; also extracts silu(gate) ----
__global__ __launch_bounds__(256) void conv_silu(const float* __restrict__ proj,
                                                 const float* __restrict__ convw,
                                                 float* __restrict__ hs,
                                                 short* __restrict__ hsb,
                                                 float* __restrict__ gate_s) {
  int idx = blockIdx.x * 256 + threadIdx.x;   // over L_*I_
  int t = idx >> 11, i = idx & (I_ - 1);
  int col = ((i >> 7) << 8) + 128 + (i & 127);  // head*256 + 128 + (i%128)
  float4 cw = *(const float4*)(convw + i * 4);
  const float* p = proj + (size_t)t * (2 * I_) + col;
  float acc = cw.w * p[0];
  if (t >= 1) acc += cw.z * p[-(2 * I_)];
  if (t >= 2) acc += cw.y * p[-(2 * I_) * 2];
  if (t >= 3) acc += cw.x * p[-(2 * I_) * 3];
  float h = acc / (1.f + __expf(-acc));   // silu
  hs[idx] = h;
  hsb[idx] = f2bf(h);
  float g = p[-128];                      // gate element for channel i
  gate_s[idx] = g / (1.f + __expf(-g));   // silu(gate)
}

// ---- RMSNorms (B, C, ts) + dt = ts@dt_proj + softplus(dt + bias) ----
__global__ __launch_bounds__(256) void norm_dt(const float* __restrict__ sp,
                                               const float* __restrict__ Bw,
                                               const float* __restrict__ Cw,
                                               const float* __restrict__ dtw,
                                               const float* __restrict__ Wdt,
                                               const float* __restrict__ bias,
                                               float* __restrict__ Bo,
                                               float* __restrict__ Co,
                                               float* __restrict__ delta) {
  int lane = threadIdx.x & 63, w = threadIdx.x >> 6;
  int t = blockIdx.x * 4 + w;
  const float* row = sp + (size_t)t * 256;
  float v0 = row[lane], v1 = row[64 + lane], v2 = row[128 + lane], v3 = row[192 + lane];
  float sB = v0 * v0, sC = v1 * v1, sT = v2 * v2 + v3 * v3;
#pragma unroll
  for (int off = 32; off; off >>= 1) {
    sB += __shfl_xor(sB, off);
    sC += __shfl_xor(sC, off);
    sT += __shfl_xor(sT, off);
  }
  float rB = rsqrtf(sB * (1.f / 64) + 1e-6f);
  float rC = rsqrtf(sC * (1.f / 64) + 1e-6f);
  float rT = rsqrtf(sT * (1.f / 128) + 1e-6f);
  Bo[t * 64 + lane] = v0 * rB * Bw[lane];
  Co[t * 64 + lane] = v1 * rC * Cw[lane];
  float t2 = v2 * rT * dtw[lane], t3 = v3 * rT * dtw[64 + lane];
  float p[NH_];
  const float* w0 = Wdt + lane * NH_;
  const float* w1 = Wdt + (64 + lane) * NH_;
#pragma unroll
  for (int h = 0; h < NH_; ++h) p[h] = t2 * w0[h] + t3 * w1[h];
#pragma unroll
  for (int off = 32; off; off >>= 1)
#pragma unroll
    for (int h = 0; h < NH_; ++h) p[h] += __shfl_xor(p[h], off);
  if (lane == 0) {
#pragma unroll
    for (int h = 0; h < NH_; ++h) {
      float x = p[h] + bias[h];
      delta[t * NH_ + h] = (x > 20.f) ? x : log1pf(__expf(x));
    }
  }
}

// ---- per-(chunk, head) delta sums ----
__global__ __launch_bounds__(512) void chunk_sums(const float* __restrict__ delta,
                                                  float* __restrict__ sumd) {
  int t = blockIdx.x * 512 + threadIdx.x;   // NCH_*16 = 1024
  int c = t >> 4, h = t & 15;
  float s = 0.f;
  const float* p = delta + (size_t)c * CT_ * NH_ + h;
#pragma unroll 8
  for (int j = 0; j < CT_; ++j) s += p[(size_t)j * NH_];
  sumd[t] = s;
}

// ======================= chunked selective scan ==========================
// Thread owns 2 channels (i, i+32) x 32 states: each B/C b128 read feeds 8
// FMA+exp ops.  NCH=64 chunks -> 2048 waves (2/SIMD).  delta via readlane;
// y combined across n-halves with ONE __shfl_xor(32) per step (ownership
// trick -> coalesced stores).  st layout [chunk][n][i] (coalesced in i).

__device__ __forceinline__ float rdlane(float v, int l) {
  return __builtin_bit_cast(float, __builtin_amdgcn_readlane(__builtin_bit_cast(int, v), l));
}

// ---- phase 1: local scan from zero (state only) ----
__global__ __launch_bounds__(256) void scan1(const float* __restrict__ hs,     // [L+1, I]
                                             const float* __restrict__ Bm,     // [L, N]
                                             const float* __restrict__ delta,  // [L, NH]
                                             const float* __restrict__ A,      // [I, N]
                                             float* __restrict__ st) {         // [NCH][N][I]
  __shared__ float sB[CT_ * 64];              // 8 KB
  int tid = threadIdx.x;
  int lane = tid & 63, wv = tid >> 6;
  int c0 = blockIdx.x * 256 + wv * 64;
  int cl = lane & 31, nh = lane >> 5;
  int chunk = blockIdx.y;
  int t0 = chunk * CT_;
  int head = c0 >> 7;
  int i0 = c0 + cl, i1 = i0 + 32;
  int nb = nh * 32;

  { const float4* B4 = (const float4*)(Bm + (size_t)t0 * 64);
    float4* S4 = (float4*)sB;
    S4[tid] = B4[tid];
    S4[256 + tid] = B4[256 + tid]; }
  float d_r = delta[(size_t)(t0 + cl) * NH_ + head];

  float a0[32], a1[32], s0[32], s1[32];
#pragma unroll
  for (int q = 0; q < 8; ++q) {
    float4 av = *(const float4*)&A[(size_t)i0 * 64 + nb + q * 4];
    float4 aw = *(const float4*)&A[(size_t)i1 * 64 + nb + q * 4];
    a0[q*4+0]=av.x; a0[q*4+1]=av.y; a0[q*4+2]=av.z; a0[q*4+3]=av.w;
    a1[q*4+0]=aw.x; a1[q*4+1]=aw.y; a1[q*4+2]=aw.z; a1[q*4+3]=aw.w;
  }
#pragma unroll
  for (int n = 0; n < 32; ++n) { s0[n] = 0.f; s1[n] = 0.f; }
  __syncthreads();

  const float* up = hs + (size_t)t0 * I_;
  float u0n = up[i0], u1n = up[i1];
#pragma unroll 1
  for (int t = 0; t < CT_; ++t) {
    float u0 = u0n, u1 = u1n;
    u0n = up[(size_t)(t + 1) * I_ + i0];     // over-reads pad row at end
    u1n = up[(size_t)(t + 1) * I_ + i1];
    float dlt = rdlane(d_r, t);
    float du0 = dlt * u0, du1 = dlt * u1;
    const float* bt = &sB[t * 64 + nb];
#pragma unroll
    for (int q = 0; q < 8; ++q) {
      float4 b4 = *(const float4*)&bt[q * 4];
#pragma unroll
      for (int j = 0; j < 4; ++j) {
        int n = q * 4 + j; float bb = (&b4.x)[j];
        s0[n] = s0[n] * __expf(dlt * a0[n]) + du0 * bb;
        s1[n] = s1[n] * __expf(dlt * a1[n]) + du1 * bb;
      }
    }
  }
  size_t base = ((size_t)chunk << 17) + i0;
#pragma unroll
  for (int n = 0; n < 32; ++n) {
    st[base + ((size_t)(nb + n) << 11)] = s0[n];
    st[base + ((size_t)(nb + n) << 11) + 32] = s1[n];
  }
}

// ---- phase 2: sequential combine; rewrites st[c] with INCOMING state ----
__global__ __launch_bounds__(512) void scan2(const float* __restrict__ A,
                                             const float* __restrict__ sumd,  // [NCH*16]
                                             float* __restrict__ st) {        // [NCH][N][I]
  int g = blockIdx.x * 512 + threadIdx.x;    // over N*I = 131072
  int i = g & (I_ - 1), n = g >> 11;
  int h = i >> 7;
  float aV = A[((size_t)i << 6) + n];
  float s = 0.f;
#pragma unroll 1
  for (int c = 0; c < NCH_; ++c) {
    float gfac = __expf(aV * sumd[c * 16 + h]);
    float loc = st[((size_t)c << 17) + g];
    st[((size_t)c << 17) + g] = s;            // incoming state for chunk c
    s = s * gfac + loc;
  }
}

// ---- phase 3: recompute with incoming state + y + fused epilogue ----
__global__ __launch_bounds__(256) void scan3(const float* __restrict__ hs,     // [L+1, I]
                                             const float* __restrict__ Bm,     // [L, N]
                                             const float* __restrict__ Cm,     // [L, N]
                                             const float* __restrict__ delta,  // [L, NH]
                                             const float* __restrict__ A,      // [I, N]
                                             const float* __restrict__ Dv,     // [I]
                                             const float* __restrict__ gate_s, // [L, I] silu(gate)
                                             const float* __restrict__ st,     // [NCH][N][I]
                                             short* __restrict__ ybf) {        // [L, I] bf16
  __shared__ float sB[CT_ * 64], sC[CT_ * 64];   // 16 KB
  int tid = threadIdx.x;
  int lane = tid & 63, wv = tid >> 6;
  int c0 = blockIdx.x * 256 + wv * 64;
  int cl = lane & 31, nh = lane >> 5;
  int chunk = blockIdx.y;
  int t0 = chunk * CT_;
  int head = c0 >> 7;
  int i0 = c0 + cl, i1 = i0 + 32;
  int nb = nh * 32;

  { const float4* B4 = (const float4*)(Bm + (size_t)t0 * 64);
    const float4* C4 = (const float4*)(Cm + (size_t)t0 * 64);
    float4* SB4 = (float4*)sB;
    float4* SC4 = (float4*)sC;
    SB4[tid] = B4[tid];       SB4[256 + tid] = B4[256 + tid];
    SC4[tid] = C4[tid];       SC4[256 + tid] = C4[256 + tid]; }
  float d_r = delta[(size_t)(t0 + cl) * NH_ + head];
  float D_own = Dv[c0 + lane];

  float a0[32], a1[32], s0[32], s1[32];
#pragma unroll
  for (int q = 0; q < 8; ++q) {
    float4 av = *(const float4*)&A[(size_t)i0 * 64 + nb + q * 4];
    float4 aw = *(const float4*)&A[(size_t)i1 * 64 + nb + q * 4];
    a0[q*4+0]=av.x; a0[q*4+1]=av.y; a0[q*4+2]=av.z; a0[q*4+3]=av.w;
    a1[q*4+0]=aw.x; a1[q*4+1]=aw.y; a1[q*4+2]=aw.z; a1[q*4+3]=aw.w;
  }
  { size_t base = ((size_t)chunk << 17) + i0;
#pragma unroll
    for (int n = 0; n < 32; ++n) {
      s0[n] = st[base + ((size_t)(nb + n) << 11)];
      s1[n] = st[base + ((size_t)(nb + n) << 11) + 32];
    } }
  __syncthreads();

  const float* up = hs + (size_t)t0 * I_;
  const float* gp = gate_s + (size_t)t0 * I_ + c0 + lane;
  short* yp = ybf + (size_t)t0 * I_ + c0 + lane;
  float u0n = up[i0], u1n = up[i1];
#pragma unroll 1
  for (int t = 0; t < CT_; ++t) {
    float u0 = u0n, u1 = u1n;
    u0n = up[(size_t)(t + 1) * I_ + i0];
    u1n = up[(size_t)(t + 1) * I_ + i1];
    float gv = gp[(size_t)t * I_];
    float dlt = rdlane(d_r, t);
    float du0 = dlt * u0, du1 = dlt * u1;
    const float* bt = &sB[t * 64 + nb];
    const float* ct = &sC[t * 64 + nb];
    float p0 = 0.f, p1 = 0.f;
#pragma unroll
    for (int q = 0; q < 8; ++q) {
      float4 b4 = *(const float4*)&bt[q * 4];
      float4 c4 = *(const float4*)&ct[q * 4];
#pragma unroll
      for (int j = 0; j < 4; ++j) {
        int n = q * 4 + j;
        float bb = (&b4.x)[j], cc = (&c4.x)[j];
        s0[n] = s0[n] * __expf(dlt * a0[n]) + du0 * bb;
        p0 += s0[n] * cc;
        s1[n] = s1[n] * __expf(dlt * a1[n]) + du1 * bb;
        p1 += s1[n] * cc;
      }
    }
    // combine n-halves; lane l ends with full y for channel c0+l
    float snd = (lane < 32) ? p1 : p0;
    snd = __shfl_xor(snd, 32);
    float y = ((lane < 32) ? p0 : p1) + snd;
    float u_own = (lane < 32) ? u0 : u1;
    y += D_own * u_own;
    yp[(size_t)t * I_] = f2bf(y * gv);
  }
}

extern "C" void kernel_launch(void* const* d_in, const int* in_sizes, int n_in,
                              void* d_out, int out_size, void* d_ws, size_t ws_size,
                              hipStream_t stream) {
  const float* hidden  = (const float*)d_in[0];
  const float* inproj  = (const float*)d_in[1];
  const float* convw   = (const float*)d_in[2];
  const float* bcdtw   = (const float*)d_in[3];
  const float* dtnw    = (const float*)d_in[4];
  const float* Bnw     = (const float*)d_in[5];
  const float* Cnw     = (const float*)d_in[6];
  const float* dtpw    = (const float*)d_in[7];
  const float* dtbias  = (const float*)d_in[8];
  const float* Amat    = (const float*)d_in[9];
  const float* Dvec    = (const float*)d_in[10];
  const float* outproj = (const float*)d_in[11];
  float* out = (float*)d_out;

  char* ws = (char*)d_ws;
  short* inproj_p  = (short*)ws; ws += (size_t)H_ * 2 * I_ * 2;   // 16 MB
  short* bcdt_p    = (short*)ws; ws += (size_t)I_ * 256 * 2;
  short* outproj_p = (short*)ws; ws += (size_t)I_ * H_ * 2;
  short* hid_b     = (short*)ws; ws += (size_t)L_ * H_ * 2;
  float* proj      = (float*)ws; ws += (size_t)L_ * 2 * I_ * 4;   // 32 MB
  float* hs        = (float*)ws; ws += (size_t)(L_ + 1) * I_ * 4; // +1 pad row
  short* hs_b      = (short*)ws; ws += (size_t)L_ * I_ * 2;
  float* gate_s    = (float*)ws; ws += (size_t)L_ * I_ * 4;       // 16 MB
  float* ssmp      = (float*)ws; ws += (size_t)L_ * 256 * 4;
  float* Bmat      = (float*)ws; ws += (size_t)L_ * NS_ * 4;
  float* Cmat      = (float*)ws; ws += (size_t)L_ * NS_ * 4;
  float* delta     = (float*)ws; ws += (size_t)L_ * NH_ * 4;
  short* y_b       = (short*)ws; ws += (size_t)L_ * I_ * 2;
  float* sumd      = (float*)ws; ws += NCH_ * 16 * 4;
  // chunk-state buffer [NCH][N][I] f32 = 32 MB: aliases proj, which is dead
  // after conv_silu (gate extracted to gate_s).  Stream-ordered each launch.
  float* sstate    = (float*)proj;

  pack_w<<<(H_ * 2 * I_ + 255) / 256, 256, 0, stream>>>(inproj, inproj_p, H_ * 2 * I_, 12);
  pack_w<<<(I_ * 256 + 255) / 256, 256, 0, stream>>>(bcdtw, bcdt_p, I_ * 256, 8);
  pack_w<<<(I_ * H_ + 255) / 256, 256, 0, stream>>>(outproj, outproj_p, I_ * H_, 11);
  cast_bf<<<(L_ * H_ + 255) / 256, 256, 0, stream>>>(hidden, hid_b, L_ * H_);

  gemm_bf16<<<dim3(L_ / 128, (2 * I_) / 128), 256, 0, stream>>>(hid_b, inproj_p, proj, L_, 2 * I_, H_);
  conv_silu<<<(L_ * I_) / 256, 256, 0, stream>>>(proj, convw, hs, hs_b, gate_s);
  gemm_bf16<<<dim3(L_ / 128, 256 / 128), 256, 0, stream>>>(hs_b, bcdt_p, ssmp, L_, 256, I_);
  norm_dt<<<L_ / 4, 256, 0, stream>>>(ssmp, Bnw, Cnw, dtnw, dtpw, dtbias, Bmat, Cmat, delta);

  chunk_sums<<<(NCH_ * 16) / 512, 512, 0, stream>>>(delta, sumd);
  scan1<<<dim3(I_ / 256, NCH_), 256, 0, stream>>>(hs, Bmat, delta, Amat, sstate);
  scan2<<<(I_ * 64) / 512, 512, 0, stream>>>(Amat, sumd, sstate);
  scan3<<<dim3(I_ / 256, NCH_), 256, 0, stream>>>(hs, Bmat, Cmat, delta, Amat, Dvec, gate_s, sstate, y_b);

  gemm_bf16<<<dim3(L_ / 128, H_ / 128), 256, 0, stream>>>(y_b, outproj_p, out, L_, H_, I_);
}

// Round 9
// 310.427 us; speedup vs baseline: 1.7327x; 1.1993x over previous
//
#include <hip/hip_runtime.h>
#include <hip/hip_bf16.h>

// dims (fixed per reference)
#define L_   2048
#define H_   2048
#define I_   2048
#define NH_  16
#define HPH_ 128
#define NS_  64
#define R_   128
#define NCH_ 64     // chunks
#define CT_  32     // steps per chunk

typedef __attribute__((ext_vector_type(8))) short s16x8;
typedef __attribute__((ext_vector_type(4))) float f32x4;

__device__ __forceinline__ short f2bf(float x) {
  unsigned u = __builtin_bit_cast(unsigned, x);
  u += 0x7fff + ((u >> 16) & 1);   // round-to-nearest-even
  return (short)(u >> 16);
}

// async global->LDS, 16B per lane; LDS dest = wave-uniform base + lane*16
__device__ __forceinline__ void gll16(const void* g, void* l) {
  __builtin_amdgcn_global_load_lds(
      (__attribute__((address_space(1))) void*)(void*)g,
      (__attribute__((address_space(3))) void*)l, 16, 0, 0);
}

// ---- pack weight W[K][N] (f32 row-major) -> Wp[(k>>3)][n][k&7] bf16 ----
__global__ __launch_bounds__(256) void pack_w(const float* __restrict__ W,
                                              short* __restrict__ Wp,
                                              int KN, int logN) {
  int idx = blockIdx.x * 256 + threadIdx.x;
  if (idx >= KN) return;
  int k = idx >> logN;
  int n = idx & ((1 << logN) - 1);
  Wp[((size_t)(k >> 3) << (logN + 3)) + ((size_t)n << 3) + (k & 7)] = f2bf(W[idx]);
}

__global__ __launch_bounds__(256) void cast_bf(const float* __restrict__ X,
                                               short* __restrict__ Xb, int nElem) {
  int idx = blockIdx.x * 256 + threadIdx.x;
  if (idx < nElem) Xb[idx] = f2bf(X[idx]);
}

// ---- staged bf16 MFMA GEMM (m97 structure): C[M,N] = A[M,K] * B[K,N] ----
// A row-major bf16 (LDS tile XOR-swizzled via pre-swizzled global source),
// B packed [k/8][n][k%8] (linear LDS).  BK=64, single-buffered, 2 barriers.
template<int BM>
__global__ __launch_bounds__(256) void gemm_st(const short* __restrict__ A,
                                               const short* __restrict__ Bp,
                                               float* __restrict__ C,
                                               int M, int N, int K) {
  constexpr int MI = BM / 32;                 // m-fragments per wave
  __shared__ short sA[BM * 64];               // [BM][64] bf16, swizzled
  __shared__ short sB[8 * 128 * 8];           // [kg][n][8] bf16, linear
  int tid = threadIdx.x;
  int lane = tid & 63, wid = tid >> 6;
  int wr = wid >> 1, wc = wid & 1;
  int l15 = lane & 15, l16 = lane >> 4;
  int bm = blockIdx.x * BM, bn = blockIdx.y * 128;

  f32x4 acc[MI][4] = {};

  // staging addresses
  int arow = lane >> 3;                       // row within 8-row group
  int acolb = ((lane & 7) ^ arow) * 16;       // inverse-swizzled source byte
  const char* Ag = (const char*)(A + (size_t)bm * K) + acolb;
  const char* Bg = (const char*)(Bp + (size_t)bn * 8);

  for (int k0 = 0; k0 < K; k0 += 64) {
    __syncthreads();                          // previous compute done
#pragma unroll
    for (int q = 0; q < BM / 32; ++q) {       // stage A: 1KB per inst
      int rbase = (q * 4 + wid) * 8;
      gll16(Ag + ((size_t)(rbase + arow) * K + k0) * 2,
            (char*)sA + rbase * 128);
    }
#pragma unroll
    for (int q = 0; q < 4; ++q) {             // stage B: 1KB per inst
      int c = q * 4 + wid;
      int kg = c >> 1, nh = (c & 1) * 64;
      gll16(Bg + ((size_t)(k0 / 8 + kg) * N * 8 + (size_t)(nh + lane) * 8) * 2,
            (char*)sB + kg * 2048 + nh * 16);
    }
    __syncthreads();                          // compiler drains vmcnt before barrier

#pragma unroll
    for (int kk = 0; kk < 64; kk += 32) {
      s16x8 a[MI], b[4];
#pragma unroll
      for (int mi = 0; mi < MI; ++mi) {
        int row = wr * (BM / 2) + mi * 16 + l15;
        int kb = ((kk + l16 * 8) * 2) ^ ((row & 7) << 4);   // swizzled read
        a[mi] = *(const s16x8*)((const char*)sA + row * 128 + kb);
      }
#pragma unroll
      for (int ni = 0; ni < 4; ++ni) {
        int n = wc * 64 + ni * 16 + l15;
        int kg = (kk >> 3) + l16;
        b[ni] = *(const s16x8*)((const char*)sB + (kg * 128 + n) * 16);
      }
#pragma unroll
      for (int mi = 0; mi < MI; ++mi)
#pragma unroll
        for (int ni = 0; ni < 4; ++ni)
          acc[mi][ni] = __builtin_amdgcn_mfma_f32_16x16x32_bf16(a[mi], b[ni], acc[mi][ni], 0, 0, 0);
    }
  }
#pragma unroll
  for (int mi = 0; mi < MI; ++mi) {
    int row0 = bm + wr * (BM / 2) + mi * 16 + l16 * 4;
#pragma unroll
    for (int ni = 0; ni < 4; ++ni) {
      int col = bn + wc * 64 + ni * 16 + l15;
#pragma unroll
      for (int r = 0; r < 4; ++r)
        C[(size_t)(row0 + r) * N + col] = acc[mi][ni][r];
    }
  }
}

// ---- causal depthwise conv (K=4) + SiLU; also extracts silu(gate) ----
__global__ __launch_bounds__(256) void conv_silu(const float* __restrict__ proj,
                                                 const float* __restrict__ convw,
                                                 float* __restrict__ hs,
                                                 short* __restrict__ hsb,
                                                 float* __restrict__ gate_s) {
  int idx = blockIdx.x * 256 + threadIdx.x;   // over L_*I_
  int t = idx >> 11, i = idx & (I_ - 1);
  int col = ((i >> 7) << 8) + 128 + (i & 127);  // head*256 + 128 + (i%128)
  float4 cw = *(const float4*)(convw + i * 4);
  const float* p = proj + (size_t)t * (2 * I_) + col;
  float acc = cw.w * p[0];
  if (t >= 1) acc += cw.z * p[-(2 * I_)];
  if (t >= 2) acc += cw.y * p[-(2 * I_) * 2];
  if (t >= 3) acc += cw.x * p[-(2 * I_) * 3];
  float h = acc / (1.f + __expf(-acc));   // silu
  hs[idx] = h;
  hsb[idx] = f2bf(h);
  float g = p[-128];                      // gate element for channel i
  gate_s[idx] = g / (1.f + __expf(-g));   // silu(gate)
}

// ---- RMSNorms (B, C, ts) + dt = ts@dt_proj + softplus(dt + bias) ----
__global__ __launch_bounds__(256) void norm_dt(const float* __restrict__ sp,
                                               const float* __restrict__ Bw,
                                               const float* __restrict__ Cw,
                                               const float* __restrict__ dtw,
                                               const float* __restrict__ Wdt,
                                               const float* __restrict__ bias,
                                               float* __restrict__ Bo,
                                               float* __restrict__ Co,
                                               float* __restrict__ delta) {
  int lane = threadIdx.x & 63, w = threadIdx.x >> 6;
  int t = blockIdx.x * 4 + w;
  const float* row = sp + (size_t)t * 256;
  float v0 = row[lane], v1 = row[64 + lane], v2 = row[128 + lane], v3 = row[192 + lane];
  float sB = v0 * v0, sC = v1 * v1, sT = v2 * v2 + v3 * v3;
#pragma unroll
  for (int off = 32; off; off >>= 1) {
    sB += __shfl_xor(sB, off);
    sC += __shfl_xor(sC, off);
    sT += __shfl_xor(sT, off);
  }
  float rB = rsqrtf(sB * (1.f / 64) + 1e-6f);
  float rC = rsqrtf(sC * (1.f / 64) + 1e-6f);
  float rT = rsqrtf(sT * (1.f / 128) + 1e-6f);
  Bo[t * 64 + lane] = v0 * rB * Bw[lane];
  Co[t * 64 + lane] = v1 * rC * Cw[lane];
  float t2 = v2 * rT * dtw[lane], t3 = v3 * rT * dtw[64 + lane];
  float p[NH_];
  const float* w0 = Wdt + lane * NH_;
  const float* w1 = Wdt + (64 + lane) * NH_;
#pragma unroll
  for (int h = 0; h < NH_; ++h) p[h] = t2 * w0[h] + t3 * w1[h];
#pragma unroll
  for (int off = 32; off; off >>= 1)
#pragma unroll
    for (int h = 0; h < NH_; ++h) p[h] += __shfl_xor(p[h], off);
  if (lane == 0) {
#pragma unroll
    for (int h = 0; h < NH_; ++h) {
      float x = p[h] + bias[h];
      delta[t * NH_ + h] = (x > 20.f) ? x : log1pf(__expf(x));
    }
  }
}

// ---- per-(chunk, head) delta sums ----
__global__ __launch_bounds__(512) void chunk_sums(const float* __restrict__ delta,
                                                  float* __restrict__ sumd) {
  int t = blockIdx.x * 512 + threadIdx.x;   // NCH_*16 = 1024
  int c = t >> 4, h = t & 15;
  float s = 0.f;
  const float* p = delta + (size_t)c * CT_ * NH_ + h;
#pragma unroll 8
  for (int j = 0; j < CT_; ++j) s += p[(size_t)j * NH_];
  sumd[t] = s;
}

// ======================= chunked selective scan ==========================
__device__ __forceinline__ float rdlane(float v, int l) {
  return __builtin_bit_cast(float, __builtin_amdgcn_readlane(__builtin_bit_cast(int, v), l));
}

// ---- phase 1: local scan from zero (state only) ----
__global__ __launch_bounds__(256) void scan1(const float* __restrict__ hs,     // [L+1, I]
                                             const float* __restrict__ Bm,     // [L, N]
                                             const float* __restrict__ delta,  // [L, NH]
                                             const float* __restrict__ A,      // [I, N]
                                             float* __restrict__ st) {         // [NCH][N][I]
  __shared__ float sB[CT_ * 64];              // 8 KB
  int tid = threadIdx.x;
  int lane = tid & 63, wv = tid >> 6;
  int c0 = blockIdx.x * 256 + wv * 64;
  int cl = lane & 31, nh = lane >> 5;
  int chunk = blockIdx.y;
  int t0 = chunk * CT_;
  int head = c0 >> 7;
  int i0 = c0 + cl, i1 = i0 + 32;
  int nb = nh * 32;

  { const float4* B4 = (const float4*)(Bm + (size_t)t0 * 64);
    float4* S4 = (float4*)sB;
    S4[tid] = B4[tid];
    S4[256 + tid] = B4[256 + tid]; }
  float d_r = delta[(size_t)(t0 + cl) * NH_ + head];

  float a0[32], a1[32], s0[32], s1[32];
#pragma unroll
  for (int q = 0; q < 8; ++q) {
    float4 av = *(const float4*)&A[(size_t)i0 * 64 + nb + q * 4];
    float4 aw = *(const float4*)&A[(size_t)i1 * 64 + nb + q * 4];
    a0[q*4+0]=av.x; a0[q*4+1]=av.y; a0[q*4+2]=av.z; a0[q*4+3]=av.w;
    a1[q*4+0]=aw.x; a1[q*4+1]=aw.y; a1[q*4+2]=aw.z; a1[q*4+3]=aw.w;
  }
#pragma unroll
  for (int n = 0; n < 32; ++n) { s0[n] = 0.f; s1[n] = 0.f; }
  __syncthreads();

  const float* up = hs + (size_t)t0 * I_;
  float u0n = up[i0], u1n = up[i1];
#pragma unroll 1
  for (int t = 0; t < CT_; ++t) {
    float u0 = u0n, u1 = u1n;
    u0n = up[(size_t)(t + 1) * I_ + i0];     // over-reads pad row at end
    u1n = up[(size_t)(t + 1) * I_ + i1];
    float dlt = rdlane(d_r, t);
    float du0 = dlt * u0, du1 = dlt * u1;
    const float* bt = &sB[t * 64 + nb];
#pragma unroll
    for (int q = 0; q < 8; ++q) {
      float4 b4 = *(const float4*)&bt[q * 4];
#pragma unroll
      for (int j = 0; j < 4; ++j) {
        int n = q * 4 + j; float bb = (&b4.x)[j];
        s0[n] = s0[n] * __expf(dlt * a0[n]) + du0 * bb;
        s1[n] = s1[n] * __expf(dlt * a1[n]) + du1 * bb;
      }
    }
  }
  size_t base = ((size_t)chunk << 17) + i0;
#pragma unroll
  for (int n = 0; n < 32; ++n) {
    st[base + ((size_t)(nb + n) << 11)] = s0[n];
    st[base + ((size_t)(nb + n) << 11) + 32] = s1[n];
  }
}

// ---- phase 2: sequential combine; rewrites st[c] with INCOMING state ----
__global__ __launch_bounds__(512) void scan2(const float* __restrict__ A,
                                             const float* __restrict__ sumd,  // [NCH*16]
                                             float* __restrict__ st) {        // [NCH][N][I]
  int g = blockIdx.x * 512 + threadIdx.x;    // over N*I = 131072
  int i = g & (I_ - 1), n = g >> 11;
  int h = i >> 7;
  float aV = A[((size_t)i << 6) + n];
  float s = 0.f;
#pragma unroll 1
  for (int c = 0; c < NCH_; ++c) {
    float gfac = __expf(aV * sumd[c * 16 + h]);
    float loc = st[((size_t)c << 17) + g];
    st[((size_t)c << 17) + g] = s;            // incoming state for chunk c
    s = s * gfac + loc;
  }
}

// ---- phase 3: recompute with incoming state + y + fused epilogue ----
__global__ __launch_bounds__(256) void scan3(const float* __restrict__ hs,     // [L+1, I]
                                             const float* __restrict__ Bm,     // [L, N]
                                             const float* __restrict__ Cm,     // [L, N]
                                             const float* __restrict__ delta,  // [L, NH]
                                             const float* __restrict__ A,      // [I, N]
                                             const float* __restrict__ Dv,     // [I]
                                             const float* __restrict__ gate_s, // [L, I] silu(gate)
                                             const float* __restrict__ st,     // [NCH][N][I]
                                             short* __restrict__ ybf) {        // [L, I] bf16
  __shared__ float sB[CT_ * 64], sC[CT_ * 64];   // 16 KB
  int tid = threadIdx.x;
  int lane = tid & 63, wv = tid >> 6;
  int c0 = blockIdx.x * 256 + wv * 64;
  int cl = lane & 31, nh = lane >> 5;
  int chunk = blockIdx.y;
  int t0 = chunk * CT_;
  int head = c0 >> 7;
  int i0 = c0 + cl, i1 = i0 + 32;
  int nb = nh * 32;

  { const float4* B4 = (const float4*)(Bm + (size_t)t0 * 64);
    const float4* C4 = (const float4*)(Cm + (size_t)t0 * 64);
    float4* SB4 = (float4*)sB;
    float4* SC4 = (float4*)sC;
    SB4[tid] = B4[tid];       SB4[256 + tid] = B4[256 + tid];
    SC4[tid] = C4[tid];       SC4[256 + tid] = C4[256 + tid]; }
  float d_r = delta[(size_t)(t0 + cl) * NH_ + head];
  float D_own = Dv[c0 + lane];

  float a0[32], a1[32], s0[32], s1[32];
#pragma unroll
  for (int q = 0; q < 8; ++q) {
    float4 av = *(const float4*)&A[(size_t)i0 * 64 + nb + q * 4];
    float4 aw = *(const float4*)&A[(size_t)i1 * 64 + nb + q * 4];
    a0[q*4+0]=av.x; a0[q*4+1]=av.y; a0[q*4+2]=av.z; a0[q*4+3]=av.w;
    a1[q*4+0]=aw.x; a1[q*4+1]=aw.y; a1[q*4+2]=aw.z; a1[q*4+3]=aw.w;
  }
  { size_t base = ((size_t)chunk << 17) + i0;
#pragma unroll
    for (int n = 0; n < 32; ++n) {
      s0[n] = st[base + ((size_t)(nb + n) << 11)];
      s1[n] = st[base + ((size_t)(nb + n) << 11) + 32];
    } }
  __syncthreads();

  const float* up = hs + (size_t)t0 * I_;
  const float* gp = gate_s + (size_t)t0 * I_ + c0 + lane;
  short* yp = ybf + (size_t)t0 * I_ + c0 + lane;
  float u0n = up[i0], u1n = up[i1];
#pragma unroll 1
  for (int t = 0; t < CT_; ++t) {
    float u0 = u0n, u1 = u1n;
    u0n = up[(size_t)(t + 1) * I_ + i0];
    u1n = up[(size_t)(t + 1) * I_ + i1];
    float gv = gp[(size_t)t * I_];
    float dlt = rdlane(d_r, t);
    float du0 = dlt * u0, du1 = dlt * u1;
    const float* bt = &sB[t * 64 + nb];
    const float* ct = &sC[t * 64 + nb];
    float p0 = 0.f, p1 = 0.f;
#pragma unroll
    for (int q = 0; q < 8; ++q) {
      float4 b4 = *(const float4*)&bt[q * 4];
      float4 c4 = *(const float4*)&ct[q * 4];
#pragma unroll
      for (int j = 0; j < 4; ++j) {
        int n = q * 4 + j;
        float bb = (&b4.x)[j], cc = (&c4.x)[j];
        s0[n] = s0[n] * __expf(dlt * a0[n]) + du0 * bb;
        p0 += s0[n] * cc;
        s1[n] = s1[n] * __expf(dlt * a1[n]) + du1 * bb;
        p1 += s1[n] * cc;
      }
    }
    // combine n-halves; lane l ends with full y for channel c0+l
    float snd = (lane < 32) ? p1 : p0;
    snd = __shfl_xor(snd, 32);
    float y = ((lane < 32) ? p0 : p1) + snd;
    float u_own = (lane < 32) ? u0 : u1;
    y += D_own * u_own;
    yp[(size_t)t * I_] = f2bf(y * gv);
  }
}

extern "C" void kernel_launch(void* const* d_in, const int* in_sizes, int n_in,
                              void* d_out, int out_size, void* d_ws, size_t ws_size,
                              hipStream_t stream) {
  const float* hidden  = (const float*)d_in[0];
  const float* inproj  = (const float*)d_in[1];
  const float* convw   = (const float*)d_in[2];
  const float* bcdtw   = (const float*)d_in[3];
  const float* dtnw    = (const float*)d_in[4];
  const float* Bnw     = (const float*)d_in[5];
  const float* Cnw     = (const float*)d_in[6];
  const float* dtpw    = (const float*)d_in[7];
  const float* dtbias  = (const float*)d_in[8];
  const float* Amat    = (const float*)d_in[9];
  const float* Dvec    = (const float*)d_in[10];
  const float* outproj = (const float*)d_in[11];
  float* out = (float*)d_out;

  char* ws = (char*)d_ws;
  short* inproj_p  = (short*)ws; ws += (size_t)H_ * 2 * I_ * 2;   // 16 MB
  short* bcdt_p    = (short*)ws; ws += (size_t)I_ * 256 * 2;
  short* outproj_p = (short*)ws; ws += (size_t)I_ * H_ * 2;
  short* hid_b     = (short*)ws; ws += (size_t)L_ * H_ * 2;
  float* proj      = (float*)ws; ws += (size_t)L_ * 2 * I_ * 4;   // 32 MB
  float* hs        = (float*)ws; ws += (size_t)(L_ + 1) * I_ * 4; // +1 pad row
  short* hs_b      = (short*)ws; ws += (size_t)L_ * I_ * 2;
  float* gate_s    = (float*)ws; ws += (size_t)L_ * I_ * 4;       // 16 MB
  float* ssmp      = (float*)ws; ws += (size_t)L_ * 256 * 4;
  float* Bmat      = (float*)ws; ws += (size_t)L_ * NS_ * 4;
  float* Cmat      = (float*)ws; ws += (size_t)L_ * NS_ * 4;
  float* delta     = (float*)ws; ws += (size_t)L_ * NH_ * 4;
  short* y_b       = (short*)ws; ws += (size_t)L_ * I_ * 2;
  float* sumd      = (float*)ws; ws += NCH_ * 16 * 4;
  // chunk-state buffer [NCH][N][I] f32 = 32 MB: aliases proj, which is dead
  // after conv_silu (gate extracted to gate_s).  Stream-ordered each launch.
  float* sstate    = (float*)proj;

  pack_w<<<(H_ * 2 * I_ + 255) / 256, 256, 0, stream>>>(inproj, inproj_p, H_ * 2 * I_, 12);
  pack_w<<<(I_ * 256 + 255) / 256, 256, 0, stream>>>(bcdtw, bcdt_p, I_ * 256, 8);
  pack_w<<<(I_ * H_ + 255) / 256, 256, 0, stream>>>(outproj, outproj_p, I_ * H_, 11);
  cast_bf<<<(L_ * H_ + 255) / 256, 256, 0, stream>>>(hidden, hid_b, L_ * H_);

  gemm_st<128><<<dim3(L_ / 128, (2 * I_) / 128), 256, 0, stream>>>(hid_b, inproj_p, proj, L_, 2 * I_, H_);
  conv_silu<<<(L_ * I_) / 256, 256, 0, stream>>>(proj, convw, hs, hs_b, gate_s);
  gemm_st<64><<<dim3(L_ / 64, 256 / 128), 256, 0, stream>>>(hs_b, bcdt_p, ssmp, L_, 256, I_);
  norm_dt<<<L_ / 4, 256, 0, stream>>>(ssmp, Bnw, Cnw, dtnw, dtpw, dtbias, Bmat, Cmat, delta);

  chunk_sums<<<(NCH_ * 16) / 512, 512, 0, stream>>>(delta, sumd);
  scan1<<<dim3(I_ / 256, NCH_), 256, 0, stream>>>(hs, Bmat, delta, Amat, sstate);
  scan2<<<(I_ * 64) / 512, 512, 0, stream>>>(Amat, sumd, sstate);
  scan3<<<dim3(I_ / 256, NCH_), 256, 0, stream>>>(hs, Bmat, Cmat, delta, Amat, Dvec, gate_s, sstate, y_b);

  gemm_st<64><<<dim3(L_ / 64, H_ / 128), 256, 0, stream>>>(y_b, outproj_p, out, L_, H_, I_);
}